// Round 17
// baseline (204.792 us; speedup 1.0000x reference)
//
#include <hip/hip_runtime.h>
#include <hip/hip_bf16.h>

#define B_ 2
#define T_ 2048
#define E_ 1024
#define H_ 16
#define HD_ 64
#define NT (B_*T_)

typedef __attribute__((ext_vector_type(8))) short s16x8;
typedef __attribute__((ext_vector_type(4))) float f32x4;

using bf16 = __hip_bfloat16;

#define MFMA16(a,b,c) __builtin_amdgcn_mfma_f32_16x16x32_bf16(a,b,c,0,0,0)

__device__ inline unsigned short f2bf(float f) {
    bf16 h = __float2bfloat16(f);
    return *reinterpret_cast<unsigned short*>(&h);
}

__device__ __forceinline__ float bf2f(unsigned short u) {
    unsigned x = ((unsigned)u) << 16;
    return __uint_as_float(x);
}

__device__ __forceinline__ unsigned cvt_pk_bf16(float lo, float hi) {
    unsigned r;
    asm("v_cvt_pk_bf16_f32 %0, %1, %2" : "=v"(r) : "v"(lo), "v"(hi));
    return r;
}

__device__ __forceinline__ float exp2_fast(float x) {
    float r;
    asm("v_exp_f32 %0, %1" : "=v"(r) : "v"(x));
    return r;
}

// async global->LDS, 16B per lane. LDS dest is wave-uniform base (+ lane*16 by HW).
__device__ __forceinline__ void async_cp16(const void* g, void* l) {
    __builtin_amdgcn_global_load_lds((const __attribute__((address_space(1))) void*)g,
                                     (__attribute__((address_space(3))) void*)l,
                                     16, 0, 0);
}

// ---------------- all weight transposes + fp32->bf16, one dispatch ----------------
__global__ __launch_bounds__(256) void transpose_all(const float* __restrict__ Wq,
                                                     const float* __restrict__ Wk,
                                                     const float* __restrict__ Wv,
                                                     const float* __restrict__ Wp,
                                                     const float* __restrict__ W1,
                                                     const float* __restrict__ W2,
                                                     bf16* __restrict__ Wqkv_t,
                                                     bf16* __restrict__ W1_t,
                                                     bf16* __restrict__ W2_t) {
    __shared__ float tile[32][33];
    int id = blockIdx.x;
    const float* src; bf16* dst; int K, N, n0, k0;
    float scl = 1.0f;
    if (id < 4096) {
        int z = id >> 10, t = id & 1023;
        src = z == 0 ? Wq : z == 1 ? Wk : z == 2 ? Wv : Wp;
        if (z == 0) scl = 0.125f * 1.44269504088896f;
        dst = Wqkv_t + (size_t)z * 1048576;
        K = 1024; N = 1024; n0 = (t & 31) * 32; k0 = (t >> 5) * 32;
    } else if (id < 8192) {
        int t = id - 4096; src = W1; dst = W1_t; K = 1024; N = 4096;
        n0 = (t & 127) * 32; k0 = (t >> 7) * 32;
    } else {
        int t = id - 8192; src = W2; dst = W2_t; K = 4096; N = 1024;
        n0 = (t & 31) * 32; k0 = (t >> 5) * 32;
    }
    int tx = threadIdx.x, ty = threadIdx.y;
#pragma unroll
    for (int i = 0; i < 4; ++i)
        tile[ty + i*8][tx] = src[(size_t)(k0 + ty + i*8)*N + n0 + tx];
    __syncthreads();
#pragma unroll
    for (int i = 0; i < 4; ++i)
        dst[(size_t)(n0 + ty + i*8)*K + k0 + tx] = __float2bfloat16(tile[tx][ty + i*8] * scl);
}

// ---------------- LayerNorm (fp32 in -> bf16 out) ----------------
__global__ __launch_bounds__(256) void ln_kernel(const float* __restrict__ x,
                                                 const float* __restrict__ g,
                                                 const float* __restrict__ b,
                                                 bf16* __restrict__ h) {
    int row = blockIdx.x;
    int tid = threadIdx.x;
    const float4 xv = *reinterpret_cast<const float4*>(x + (size_t)row*E_ + tid*4);
    float s  = xv.x + xv.y + xv.z + xv.w;
    float sq = xv.x*xv.x + xv.y*xv.y + xv.z*xv.z + xv.w*xv.w;
#pragma unroll
    for (int o = 32; o > 0; o >>= 1) { s += __shfl_xor(s, o); sq += __shfl_xor(sq, o); }
    __shared__ float red[8];
    int w = tid >> 6, lane = tid & 63;
    if (lane == 0) { red[w] = s; red[4 + w] = sq; }
    __syncthreads();
    float S = red[0] + red[1] + red[2] + red[3];
    float Q = red[4] + red[5] + red[6] + red[7];
    float mu = S * (1.0f/E_);
    float var = Q * (1.0f/E_) - mu*mu;
    float rs = rsqrtf(var + 1e-5f);
    const float4 gv = *reinterpret_cast<const float4*>(g + tid*4);
    const float4 bv = *reinterpret_cast<const float4*>(b + tid*4);
    ushort4 o4;
    o4.x = f2bf((xv.x - mu)*rs*gv.x + bv.x);
    o4.y = f2bf((xv.y - mu)*rs*gv.y + bv.y);
    o4.z = f2bf((xv.z - mu)*rs*gv.z + bv.z);
    o4.w = f2bf((xv.w - mu)*rs*gv.w + bv.w);
    *reinterpret_cast<ushort4*>(h + (size_t)row*E_ + tid*4) = o4;
}

// ---------------- LayerNorm (bf16 in -> bf16 out) ----------------
__global__ __launch_bounds__(256) void ln_kernel_b(const bf16* __restrict__ x,
                                                   const float* __restrict__ g,
                                                   const float* __restrict__ b,
                                                   bf16* __restrict__ h) {
    int row = blockIdx.x;
    int tid = threadIdx.x;
    ushort4 u4 = *reinterpret_cast<const ushort4*>(x + (size_t)row*E_ + tid*4);
    float v0 = bf2f(u4.x), v1 = bf2f(u4.y), v2 = bf2f(u4.z), v3 = bf2f(u4.w);
    float s  = v0 + v1 + v2 + v3;
    float sq = v0*v0 + v1*v1 + v2*v2 + v3*v3;
#pragma unroll
    for (int o = 32; o > 0; o >>= 1) { s += __shfl_xor(s, o); sq += __shfl_xor(sq, o); }
    __shared__ float red[8];
    int w = tid >> 6, lane = tid & 63;
    if (lane == 0) { red[w] = s; red[4 + w] = sq; }
    __syncthreads();
    float S = red[0] + red[1] + red[2] + red[3];
    float Q = red[4] + red[5] + red[6] + red[7];
    float mu = S * (1.0f/E_);
    float var = Q * (1.0f/E_) - mu*mu;
    float rs = rsqrtf(var + 1e-5f);
    const float4 gv = *reinterpret_cast<const float4*>(g + tid*4);
    const float4 bv = *reinterpret_cast<const float4*>(b + tid*4);
    ushort4 o4;
    o4.x = f2bf((v0 - mu)*rs*gv.x + bv.x);
    o4.y = f2bf((v1 - mu)*rs*gv.y + bv.y);
    o4.z = f2bf((v2 - mu)*rs*gv.z + bv.z);
    o4.w = f2bf((v3 - mu)*rs*gv.w + bv.w);
    *reinterpret_cast<ushort4*>(h + (size_t)row*E_ + tid*4) = o4;
}

// ---------------- 64x64 GEMM, BK=128, 16-chunk XOR swizzle, XCD-chunked ----------
// Halves the K-step count vs BK=64 (per-step vmcnt(0)+barrier drain is the cost).
// LDS rows are 256B: swizzle 16B-chunk ^= (row&15); within each 16-lane b128
// phase lr spans 0..15 -> 2 lanes/bank-quad (free). Source pre-swizzled (rule 21).
// EPI: 1 = f32 out + bias + f32 res; 3 = bf16 out + bias + f32 res (proj);
//      4 = f32 out + bias + bf16 res (FFN2).
template<int EPI>
__global__ __launch_bounds__(256)
void gemm_k128(const bf16* __restrict__ A, const bf16* __restrict__ Bt, void* Cout,
               const float* __restrict__ bias, const void* res,
               int M, int N, int K) {
    __shared__ bf16 As[64*128];
    __shared__ bf16 Bs[64*128];
    int tid = threadIdx.x;
    int lane = tid & 63, w = tid >> 6;
    int wr = w >> 1, wc = w & 1;
    int nbx = gridDim.x;
    int hid = blockIdx.y * nbx + blockIdx.x;
    int cpx = (nbx * gridDim.y) >> 3;
    int nid = (hid & 7) * cpx + (hid >> 3);     // XCD-chunked (m157, bijective)
    int m0 = (nid / nbx) * 64, n0 = (nid % nbx) * 64;
    int lr = lane & 15, lq = lane >> 4;
    f32x4 acc[2][2] = {};
    // staging: issue i covers rows i*16 + srow; srow = w*4 + (lane>>4); phys
    // chunk = lane&15; source chunk = phys ^ (srow&15)  (i*16 doesn't affect &15)
    int srow = w*4 + (lane >> 4);
    int schunk = ((lane & 15) ^ (srow & 15)) * 8;
    const bf16* Ap = A  + (size_t)(m0 + srow)*K + schunk;
    const bf16* Bp = Bt + (size_t)(n0 + srow)*K + schunk;
    // frag read offsets: row R, kk: byte = R*256 + (((kk*4+lq) ^ (R&15)) << 4); R&15 = lr
    int aoff[2][4], boff[2][4];
#pragma unroll
    for (int m = 0; m < 2; ++m) {
        int R = wr*32 + m*16 + lr;
#pragma unroll
        for (int kk = 0; kk < 4; ++kk)
            aoff[m][kk] = R*256 + (((kk*4 + lq) ^ lr) << 4);
    }
#pragma unroll
    for (int n = 0; n < 2; ++n) {
        int R = wc*32 + n*16 + lr;
#pragma unroll
        for (int kk = 0; kk < 4; ++kk)
            boff[n][kk] = R*256 + (((kk*4 + lq) ^ lr) << 4);
    }
    for (int k0 = 0; k0 < K; k0 += 128) {
#pragma unroll
        for (int i = 0; i < 4; ++i)
            async_cp16(Ap + (size_t)(i*16)*K + k0, (char*)As + i*4096 + w*1024);
#pragma unroll
        for (int i = 0; i < 4; ++i)
            async_cp16(Bp + (size_t)(i*16)*K + k0, (char*)Bs + i*4096 + w*1024);
        __syncthreads();
        const char* Asb = (const char*)As;
        const char* Bsb = (const char*)Bs;
        s16x8 af[4][2], bfr[4][2];
#pragma unroll
        for (int m = 0; m < 2; ++m)
#pragma unroll
            for (int kk = 0; kk < 4; ++kk)
                af[kk][m] = *reinterpret_cast<const s16x8*>(Asb + aoff[m][kk]);
#pragma unroll
        for (int n = 0; n < 2; ++n)
#pragma unroll
            for (int kk = 0; kk < 4; ++kk)
                bfr[kk][n] = *reinterpret_cast<const s16x8*>(Bsb + boff[n][kk]);
        __builtin_amdgcn_s_setprio(1);
#pragma unroll
        for (int kk = 0; kk < 4; ++kk)
#pragma unroll
            for (int m = 0; m < 2; ++m)
#pragma unroll
                for (int n = 0; n < 2; ++n)
                    acc[m][n] = MFMA16(af[kk][m], bfr[kk][n], acc[m][n]);
        __builtin_amdgcn_s_setprio(0);
        __syncthreads();
    }
#pragma unroll
    for (int m = 0; m < 2; ++m) {
#pragma unroll
        for (int n = 0; n < 2; ++n) {
            int col = n0 + wc*32 + n*16 + lr;
#pragma unroll
            for (int r = 0; r < 4; ++r) {
                int row = m0 + wr*32 + m*16 + lq*4 + r;
                size_t idx = (size_t)row*N + col;
                float v = acc[m][n][r] + bias[col];
                if (EPI == 1) {
                    reinterpret_cast<float*>(Cout)[idx] =
                        v + reinterpret_cast<const float*>(res)[idx];
                } else if (EPI == 3) {
                    reinterpret_cast<bf16*>(Cout)[idx] =
                        __float2bfloat16(v + reinterpret_cast<const float*>(res)[idx]);
                } else {   // EPI == 4
                    reinterpret_cast<float*>(Cout)[idx] =
                        v + bf2f(reinterpret_cast<const unsigned short*>(res)[idx]);
                }
            }
        }
    }
}

// ---------------- 256x256 8-wave 4-phase-lookahead GEMM (QKV / FFN1) ------------
#define RD(p) (*reinterpret_cast<const s16x8*>(p))
#define MM(m,n) do { acc[m][n] = MFMA16(af[m][0], bfr[n][0], acc[m][n]); \
                     acc[m][n] = MFMA16(af[m][1], bfr[n][1], acc[m][n]); } while (0)
#define MFMAS_0 MM(0,0); MM(1,0);
#define MFMAS_1 MM(2,0); MM(3,0); MM(2,1); MM(3,1); MM(0,1); MM(1,1);
#define MFMAS_2 MM(4,0); MM(5,0); MM(4,1); MM(5,1); MM(4,2); MM(5,2); \
                MM(0,2); MM(1,2); MM(2,2); MM(3,2);
#define MFMAS_3 MM(6,0); MM(7,0); MM(6,1); MM(7,1); MM(6,2); MM(7,2); \
                MM(6,3); MM(7,3); MM(0,3); MM(1,3); MM(2,3); MM(3,3); \
                MM(4,3); MM(5,3);

template<int EPI>
__global__ __launch_bounds__(512)
void gemm8p(const bf16* __restrict__ A, const bf16* __restrict__ Bt, void* Cout,
            const float* __restrict__ bias, int M, int N, int K) {
    __shared__ char smem[131072];   // buf b at b*65536: A 32K | B 32K
    int tid = threadIdx.x;
    int lane = tid & 63, w = tid >> 6;
    int wm = w >> 2, wn = w & 3;
    int nbx = gridDim.x;
    int hid = blockIdx.y * nbx + blockIdx.x;
    int cpx = (nbx * gridDim.y) >> 3;
    int nid = (hid & 7) * cpx + (hid >> 3);     // XCD-chunked (m157, bijective)
    int m0 = (nid / nbx) * 256, n0 = (nid % nbx) * 256;
    int lr = lane & 15, lq = lane >> 4;
    f32x4 acc[8][4] = {};
    int srow = tid >> 3;
    int schunk = ((tid & 7) ^ (srow & 7)) * 8;
    const bf16* ApS = A  + (size_t)(m0 + srow)*K + schunk;
    const bf16* BpS = Bt + (size_t)(n0 + srow)*K + schunk;
    int sw4 = (lr & 7) << 4;
    int x0 = (lq*16) ^ sw4, x1 = (64 + lq*16) ^ sw4;
    int aoff[8], boff[4];
#pragma unroll
    for (int m = 0; m < 8; ++m)
        aoff[m] = ((m >> 1)*64 + wm*32 + (m & 1)*16 + lr) * 128;
#pragma unroll
    for (int n = 0; n < 4; ++n)
        boff[n] = (n*64 + wn*16 + lr) * 128;
    int nst = K >> 6;
    s16x8 af[8][2], bfr[4][2];
#pragma unroll
    for (int q = 0; q < 4; ++q) {
        async_cp16(ApS + (size_t)(q*64)*K, smem + q*8192 + w*1024);
        async_cp16(BpS + (size_t)(q*64)*K, smem + 32768 + q*8192 + w*1024);
    }
    ApS += 64; BpS += 64;
    asm volatile("s_waitcnt vmcnt(6)" ::: "memory");
    __builtin_amdgcn_sched_barrier(0);
    __builtin_amdgcn_s_barrier();
    __builtin_amdgcn_sched_barrier(0);

#define PHASE(Q) do {                                                              \
    af[2*Q][0]   = RD(bufA + aoff[2*Q]   + x0);                                    \
    af[2*Q][1]   = RD(bufA + aoff[2*Q]   + x1);                                    \
    af[2*Q+1][0] = RD(bufA + aoff[2*Q+1] + x0);                                    \
    af[2*Q+1][1] = RD(bufA + aoff[2*Q+1] + x1);                                    \
    bfr[Q][0]    = RD(bufB + boff[Q] + x0);                                        \
    bfr[Q][1]    = RD(bufB + boff[Q] + x1);                                        \
    if (more) {                                                                    \
        async_cp16(ApS + (size_t)(Q*64)*K, stA + Q*8192 + w*1024);                 \
        async_cp16(BpS + (size_t)(Q*64)*K, stA + 32768 + Q*8192 + w*1024);         \
        asm volatile("s_waitcnt vmcnt(6)" ::: "memory");                           \
    } else {                                                                       \
        if (Q == 0) asm volatile("s_waitcnt vmcnt(4)" ::: "memory");               \
        else if (Q == 1) asm volatile("s_waitcnt vmcnt(2)" ::: "memory");          \
        else if (Q == 2) asm volatile("s_waitcnt vmcnt(0)" ::: "memory");          \
    }                                                                              \
    __builtin_amdgcn_sched_barrier(0);                                             \
    __builtin_amdgcn_s_barrier();                                                  \
    __builtin_amdgcn_sched_barrier(0);                                             \
    asm volatile("s_waitcnt lgkmcnt(0)" ::: "memory");                             \
    __builtin_amdgcn_sched_barrier(0);                                             \
    __builtin_amdgcn_s_setprio(1);                                                 \
    MFMAS_##Q                                                                      \
    __builtin_amdgcn_s_setprio(0);                                                 \
    __builtin_amdgcn_sched_barrier(0);                                             \
    __builtin_amdgcn_s_barrier();                                                  \
    __builtin_amdgcn_sched_barrier(0);                                             \
} while (0)

    for (int t = 0; t < nst; ++t) {
        const char* bufA = smem + (size_t)(t & 1)*65536;
        const char* bufB = bufA + 32768;
        char* stA = smem + (size_t)((t & 1) ^ 1)*65536;
        bool more = (t + 1 < nst);
        PHASE(0);
        PHASE(1);
        PHASE(2);
        PHASE(3);
        ApS += 64; BpS += 64;
    }
#undef PHASE
#pragma unroll
    for (int m = 0; m < 8; ++m) {
#pragma unroll
        for (int n = 0; n < 4; ++n) {
            int col = n0 + n*64 + wn*16 + lr;
#pragma unroll
            for (int r = 0; r < 4; ++r) {
                int row = m0 + (m >> 1)*64 + wm*32 + (m & 1)*16 + lq*4 + r;
                float v = acc[m][n][r];
                if (EPI == 0) {
                    reinterpret_cast<bf16*>(Cout)[(size_t)row*N + col] = __float2bfloat16(v);
                } else {
                    v += bias[col];
                    v = v > 0.f ? v : 0.f;
                    reinterpret_cast<bf16*>(Cout)[(size_t)row*N + col] = __float2bfloat16(v);
                }
            }
        }
    }
}

// ---------------- V transpose: qkv v-section -> Vt [B,H,HD,T] ----------------
__global__ __launch_bounds__(256) void v_transpose(const bf16* __restrict__ qkv,
                                                   bf16* __restrict__ Vt) {
    __shared__ unsigned short tile[32][33];
    int tx = threadIdx.x, ty = threadIdx.y;
    int bh = blockIdx.z;
    int b = bh >> 4, h = bh & 15;
    int t0 = blockIdx.x * 32, d0 = blockIdx.y * 32;
    const unsigned short* src = reinterpret_cast<const unsigned short*>(qkv);
#pragma unroll
    for (int i = 0; i < 4; ++i)
        tile[ty + i*8][tx] = src[(size_t)(b*T_ + t0 + ty + i*8)*3072 + 2048 + h*64 + d0 + tx];
    __syncthreads();
    unsigned short* dst = reinterpret_cast<unsigned short*>(Vt);
#pragma unroll
    for (int i = 0; i < 4; ++i)
        dst[(size_t)(bh*64 + d0 + ty + i*8)*T_ + t0 + tx] = tile[tx][ty + i*8];
}

// ---------------- causal flash attention v8 (r11-best) --------------------------
__global__ __launch_bounds__(256)
void flash_attn(const bf16* __restrict__ qkv, const bf16* __restrict__ Vt,
                bf16* __restrict__ O) {
    __shared__ char smem[40960];   // K dbuf 16K | V dbuf 16K | P 4x2K
    int tid = threadIdx.x;
    int lane = tid & 63, w = tid >> 6;
    int lr = lane & 15, lq = lane >> 4;
    int bh = blockIdx.y, b = bh >> 4, h = bh & 15;
    int pm = (bh & 15) ^ ((bh & 16) ? 31 : 0);
    int qt = (int)(blockIdx.x ^ pm) & 31;         // complement-paired depths per CU
    int q0 = qt * 64;
    int qw = q0 + w * 16;
    const bf16* Qb = qkv + (size_t)(b*T_)*3072 + h*HD_;
    const bf16* Kb = Qb + 1024;
    const bf16* Vb = Vt + (size_t)bh * HD_ * T_;
    char* Pw = smem + 32768 + w*2048;

    int srow_ = w*8 + (lane >> 3);
    int sc_   = (((lane & 7) ^ (srow_ & 7))) * 8;
    const bf16* kS0 = Kb + (size_t)srow_*3072 + sc_;
    const bf16* kS1 = kS0 + (size_t)32*3072;
    const bf16* vS0 = Vb + (size_t)srow_*2048 + sc_;
    const bf16* vS1 = vS0 + (size_t)32*2048;
    char* kD = smem + w*1024;
    char* vD = smem + 16384 + w*1024;

    int sw4 = (lr & 7) << 4;
    int kvo[4], pwo[4];
#pragma unroll
    for (int n = 0; n < 4; ++n) {
        kvo[n] = n*2048 + lr*128 + ((lq << 4) ^ sw4);
        pwo[n] = (lr*128 + n*32 + lq*8) ^ sw4;
    }
    int pao0 = (lr*128 + lq*16) ^ sw4;
    int pao1 = (lr*128 + 64 + lq*16) ^ sw4;

    s16x8 qf[2];
#pragma unroll
    for (int kk = 0; kk < 2; ++kk)
        qf[kk] = *reinterpret_cast<const s16x8*>(Qb + (size_t)(qw + lr)*3072 + kk*32 + lq*8);
    f32x4 od[4] = {};
    const f32x4 Z4 = {0.f, 0.f, 0.f, 0.f};
    float lrun = 0.f;
    int ntiles = qt + 1;

    auto stageNext = [&](int bufi) {
        async_cp16(kS0, kD + bufi*8192);
        async_cp16(kS1, kD + bufi*8192 + 4096);
        async_cp16(vS0, vD + bufi*8192);
        async_cp16(vS1, vD + bufi*8192 + 4096);
        kS0 += 64*3072; kS1 += 64*3072; vS0 += 64; vS1 += 64;
    };

    auto step = [&](const char* Kt, const char* Vtl, bool diag, int kv0) {
        f32x4 sc[4];
        __builtin_amdgcn_s_setprio(1);
#pragma unroll
        for (int n = 0; n < 4; ++n) {
            s16x8 kf0 = *reinterpret_cast<const s16x8*>(Kt + kvo[n]);
            s16x8 kf1 = *reinterpret_cast<const s16x8*>(Kt + (kvo[n] ^ 64));
            f32x4 z = MFMA16(kf0, qf[0], Z4);   // S^T: col=q(lr), row=kv
            z = MFMA16(kf1, qf[1], z);
            sc[n] = z;
        }
        __builtin_amdgcn_s_setprio(0);
        if (diag) {
            int q = qw + lr;
#pragma unroll
            for (int n = 0; n < 4; ++n)
#pragma unroll
                for (int r = 0; r < 4; ++r)
                    if (kv0 + n*16 + lq*4 + r > q) sc[n][r] = -1e30f;
        }
        float psum = 0.f;
#pragma unroll
        for (int n = 0; n < 4; ++n) {
            float p0 = exp2_fast(sc[n][0]);
            float p1 = exp2_fast(sc[n][1]);
            float p2 = exp2_fast(sc[n][2]);
            float p3 = exp2_fast(sc[n][3]);
            psum += (p0 + p1) + (p2 + p3);
            uint2 pk;
            pk.x = cvt_pk_bf16(p0, p1);
            pk.y = cvt_pk_bf16(p2, p3);
            *reinterpret_cast<uint2*>(Pw + pwo[n]) = pk;
        }
        psum += __shfl_xor(psum, 16);
        psum += __shfl_xor(psum, 32);
        lrun += psum;
        asm volatile("" ::: "memory");
        s16x8 pa0 = *reinterpret_cast<const s16x8*>(Pw + pao0);
        s16x8 pa1 = *reinterpret_cast<const s16x8*>(Pw + pao1);
        __builtin_amdgcn_s_setprio(1);
#pragma unroll
        for (int nd = 0; nd < 4; ++nd) {
            s16x8 vf0 = *reinterpret_cast<const s16x8*>(Vtl + kvo[nd]);
            s16x8 vf1 = *reinterpret_cast<const s16x8*>(Vtl + (kvo[nd] ^ 64));
            od[nd] = MFMA16(pa0, vf0, od[nd]);
            od[nd] = MFMA16(pa1, vf1, od[nd]);
        }
        __builtin_amdgcn_s_setprio(0);
    };

    stageNext(0);
    for (int it = 0; it < ntiles - 1; ++it) {
        int curb = it & 1;
        stageNext(curb ^ 1);
        asm volatile("s_waitcnt vmcnt(4)" ::: "memory");
        __builtin_amdgcn_sched_barrier(0);
        __builtin_amdgcn_s_barrier();
        __builtin_amdgcn_sched_barrier(0);
        step(smem + curb*8192, smem + 16384 + curb*8192, false, 0);
        __builtin_amdgcn_sched_barrier(0);
        __builtin_amdgcn_s_barrier();
        __builtin_amdgcn_sched_barrier(0);
    }
    {   // peeled diagonal step
        int curb = (ntiles - 1) & 1;
        asm volatile("s_waitcnt vmcnt(0)" ::: "memory");
        __builtin_amdgcn_sched_barrier(0);
        __builtin_amdgcn_s_barrier();
        __builtin_amdgcn_sched_barrier(0);
        step(smem + curb*8192, smem + 16384 + curb*8192, true, (ntiles - 1) * 64);
    }
    float lR[4];
#pragma unroll
    for (int r = 0; r < 4; ++r) lR[r] = 1.0f / __shfl(lrun, lq*4 + r);
#pragma unroll
    for (int nd = 0; nd < 4; ++nd) {
#pragma unroll
        for (int r = 0; r < 4; ++r) {
            int row = qw + lq*4 + r;
            O[(size_t)(b*T_ + row)*E_ + h*HD_ + nd*16 + lr] = __float2bfloat16(od[nd][r] * lR[r]);
        }
    }
}

// ---------------- launch ----------------
extern "C" void kernel_launch(void* const* d_in, const int* in_sizes, int n_in,
                              void* d_out, int out_size, void* d_ws, size_t ws_size,
                              hipStream_t stream) {
    const float* x   = (const float*)d_in[0];
    const float* Wk  = (const float*)d_in[1];
    const float* Wq  = (const float*)d_in[2];
    const float* Wv  = (const float*)d_in[3];
    const float* Wp  = (const float*)d_in[4];
    const float* bp  = (const float*)d_in[5];
    const float* W1  = (const float*)d_in[6];
    const float* b1  = (const float*)d_in[7];
    const float* W2  = (const float*)d_in[8];
    const float* b2  = (const float*)d_in[9];
    const float* g1  = (const float*)d_in[10];
    const float* be1 = (const float*)d_in[11];
    const float* g2  = (const float*)d_in[12];
    const float* be2 = (const float*)d_in[13];
    float* out = (float*)d_out;

    char* ws = (char*)d_ws;
    bf16* Wqkv_t = (bf16*)(ws + 0);          //  6 MB [3072][1024] (+Wp_t after)
    bf16* Wp_t   = (bf16*)(ws + 6291456);    //  2 MB [1024][1024]
    bf16* W1_t   = (bf16*)(ws + 8388608);    //  8 MB [4096][1024]
    bf16* W2_t   = (bf16*)(ws + 16777216);   //  8 MB [1024][4096]
    bf16* h      = (bf16*)(ws + 25165824);   //  8 MB [4096][1024] (reused as h2)
    bf16* qkv    = (bf16*)(ws + 33554432);   // 24 MB [4096][3072]
    bf16* Vt     = (bf16*)(ws + 58720256);   //  8 MB [B,H,HD,T]
    bf16* attnO  = (bf16*)(ws + 67108864);   //  8 MB [4096][1024]
    bf16* ff1    = (bf16*)(ws + 33554432);   // 32 MB, reuses qkv+Vt (dead after flash)
    bool big = ws_size >= 83886080;
    bf16* x2b = (bf16*)(ws + 75497472);      //  8 MB bf16 residual (big path)

    dim3 tb(32, 8);
    transpose_all<<<12288, tb, 0, stream>>>(Wq, Wk, Wv, Wp, W1, W2, Wqkv_t, W1_t, W2_t);

    ln_kernel<<<NT, 256, 0, stream>>>(x, g1, be1, h);
    gemm8p<0><<<dim3(12, 16), 512, 0, stream>>>(h, Wqkv_t, qkv, nullptr, NT, 3072, 1024);
    v_transpose<<<dim3(64, 2, 32), tb, 0, stream>>>(qkv, Vt);
    flash_attn<<<dim3(32, 32), 256, 0, stream>>>(qkv, Vt, attnO);
    if (big) {
        gemm_k128<3><<<dim3(16, 64), 256, 0, stream>>>(attnO, Wp_t, x2b, bp, x, NT, 1024, 1024);
        ln_kernel_b<<<NT, 256, 0, stream>>>(x2b, g2, be2, h);
        gemm8p<2><<<dim3(16, 16), 512, 0, stream>>>(h, W1_t, ff1, b1, NT, 4096, 1024);
        gemm_k128<4><<<dim3(16, 64), 256, 0, stream>>>(ff1, W2_t, out, b2, x2b, NT, 1024, 4096);
    } else {
        // fallback: f32 residual staged in d_out (same-thread read-then-write is safe)
        gemm_k128<1><<<dim3(16, 64), 256, 0, stream>>>(attnO, Wp_t, out, bp, x, NT, 1024, 1024);
        ln_kernel<<<NT, 256, 0, stream>>>(out, g2, be2, h);
        gemm8p<2><<<dim3(16, 16), 512, 0, stream>>>(h, W1_t, ff1, b1, NT, 4096, 1024);
        gemm_k128<1><<<dim3(16, 64), 256, 0, stream>>>(ff1, W2_t, out, b2, out, NT, 1024, 4096);
    }
}

// Round 18
// 198.043 us; speedup vs baseline: 1.0341x; 1.0341x over previous
//
#include <hip/hip_runtime.h>
#include <hip/hip_bf16.h>

#define B_ 2
#define T_ 2048
#define E_ 1024
#define H_ 16
#define HD_ 64
#define NT (B_*T_)

typedef __attribute__((ext_vector_type(8))) short s16x8;
typedef __attribute__((ext_vector_type(4))) float f32x4;

using bf16 = __hip_bfloat16;

#define MFMA16(a,b,c) __builtin_amdgcn_mfma_f32_16x16x32_bf16(a,b,c,0,0,0)

__device__ inline unsigned short f2bf(float f) {
    bf16 h = __float2bfloat16(f);
    return *reinterpret_cast<unsigned short*>(&h);
}

__device__ __forceinline__ float bf2f(unsigned short u) {
    unsigned x = ((unsigned)u) << 16;
    return __uint_as_float(x);
}

__device__ __forceinline__ unsigned cvt_pk_bf16(float lo, float hi) {
    unsigned r;
    asm("v_cvt_pk_bf16_f32 %0, %1, %2" : "=v"(r) : "v"(lo), "v"(hi));
    return r;
}

__device__ __forceinline__ float exp2_fast(float x) {
    float r;
    asm("v_exp_f32 %0, %1" : "=v"(r) : "v"(x));
    return r;
}

// async global->LDS, 16B per lane. LDS dest is wave-uniform base (+ lane*16 by HW).
__device__ __forceinline__ void async_cp16(const void* g, void* l) {
    __builtin_amdgcn_global_load_lds((const __attribute__((address_space(1))) void*)g,
                                     (__attribute__((address_space(3))) void*)l,
                                     16, 0, 0);
}

// ---------------- all weight transposes + fp32->bf16, one dispatch ----------------
__global__ __launch_bounds__(256) void transpose_all(const float* __restrict__ Wq,
                                                     const float* __restrict__ Wk,
                                                     const float* __restrict__ Wv,
                                                     const float* __restrict__ Wp,
                                                     const float* __restrict__ W1,
                                                     const float* __restrict__ W2,
                                                     bf16* __restrict__ Wqkv_t,
                                                     bf16* __restrict__ W1_t,
                                                     bf16* __restrict__ W2_t) {
    __shared__ float tile[32][33];
    int id = blockIdx.x;
    const float* src; bf16* dst; int K, N, n0, k0;
    float scl = 1.0f;
    if (id < 4096) {
        int z = id >> 10, t = id & 1023;
        src = z == 0 ? Wq : z == 1 ? Wk : z == 2 ? Wv : Wp;
        if (z == 0) scl = 0.125f * 1.44269504088896f;
        dst = Wqkv_t + (size_t)z * 1048576;
        K = 1024; N = 1024; n0 = (t & 31) * 32; k0 = (t >> 5) * 32;
    } else if (id < 8192) {
        int t = id - 4096; src = W1; dst = W1_t; K = 1024; N = 4096;
        n0 = (t & 127) * 32; k0 = (t >> 7) * 32;
    } else {
        int t = id - 8192; src = W2; dst = W2_t; K = 4096; N = 1024;
        n0 = (t & 31) * 32; k0 = (t >> 5) * 32;
    }
    int tx = threadIdx.x, ty = threadIdx.y;
#pragma unroll
    for (int i = 0; i < 4; ++i)
        tile[ty + i*8][tx] = src[(size_t)(k0 + ty + i*8)*N + n0 + tx];
    __syncthreads();
#pragma unroll
    for (int i = 0; i < 4; ++i)
        dst[(size_t)(n0 + ty + i*8)*K + k0 + tx] = __float2bfloat16(tile[tx][ty + i*8] * scl);
}

// ---------------- LayerNorm (fp32 in -> bf16 out) ----------------
__global__ __launch_bounds__(256) void ln_kernel(const float* __restrict__ x,
                                                 const float* __restrict__ g,
                                                 const float* __restrict__ b,
                                                 bf16* __restrict__ h) {
    int row = blockIdx.x;
    int tid = threadIdx.x;
    const float4 xv = *reinterpret_cast<const float4*>(x + (size_t)row*E_ + tid*4);
    float s  = xv.x + xv.y + xv.z + xv.w;
    float sq = xv.x*xv.x + xv.y*xv.y + xv.z*xv.z + xv.w*xv.w;
#pragma unroll
    for (int o = 32; o > 0; o >>= 1) { s += __shfl_xor(s, o); sq += __shfl_xor(sq, o); }
    __shared__ float red[8];
    int w = tid >> 6, lane = tid & 63;
    if (lane == 0) { red[w] = s; red[4 + w] = sq; }
    __syncthreads();
    float S = red[0] + red[1] + red[2] + red[3];
    float Q = red[4] + red[5] + red[6] + red[7];
    float mu = S * (1.0f/E_);
    float var = Q * (1.0f/E_) - mu*mu;
    float rs = rsqrtf(var + 1e-5f);
    const float4 gv = *reinterpret_cast<const float4*>(g + tid*4);
    const float4 bv = *reinterpret_cast<const float4*>(b + tid*4);
    ushort4 o4;
    o4.x = f2bf((xv.x - mu)*rs*gv.x + bv.x);
    o4.y = f2bf((xv.y - mu)*rs*gv.y + bv.y);
    o4.z = f2bf((xv.z - mu)*rs*gv.z + bv.z);
    o4.w = f2bf((xv.w - mu)*rs*gv.w + bv.w);
    *reinterpret_cast<ushort4*>(h + (size_t)row*E_ + tid*4) = o4;
}

// ---------------- LayerNorm (bf16 in -> bf16 out) ----------------
__global__ __launch_bounds__(256) void ln_kernel_b(const bf16* __restrict__ x,
                                                   const float* __restrict__ g,
                                                   const float* __restrict__ b,
                                                   bf16* __restrict__ h) {
    int row = blockIdx.x;
    int tid = threadIdx.x;
    ushort4 u4 = *reinterpret_cast<const ushort4*>(x + (size_t)row*E_ + tid*4);
    float v0 = bf2f(u4.x), v1 = bf2f(u4.y), v2 = bf2f(u4.z), v3 = bf2f(u4.w);
    float s  = v0 + v1 + v2 + v3;
    float sq = v0*v0 + v1*v1 + v2*v2 + v3*v3;
#pragma unroll
    for (int o = 32; o > 0; o >>= 1) { s += __shfl_xor(s, o); sq += __shfl_xor(sq, o); }
    __shared__ float red[8];
    int w = tid >> 6, lane = tid & 63;
    if (lane == 0) { red[w] = s; red[4 + w] = sq; }
    __syncthreads();
    float S = red[0] + red[1] + red[2] + red[3];
    float Q = red[4] + red[5] + red[6] + red[7];
    float mu = S * (1.0f/E_);
    float var = Q * (1.0f/E_) - mu*mu;
    float rs = rsqrtf(var + 1e-5f);
    const float4 gv = *reinterpret_cast<const float4*>(g + tid*4);
    const float4 bv = *reinterpret_cast<const float4*>(b + tid*4);
    ushort4 o4;
    o4.x = f2bf((v0 - mu)*rs*gv.x + bv.x);
    o4.y = f2bf((v1 - mu)*rs*gv.y + bv.y);
    o4.z = f2bf((v2 - mu)*rs*gv.z + bv.z);
    o4.w = f2bf((v3 - mu)*rs*gv.w + bv.w);
    *reinterpret_cast<ushort4*>(h + (size_t)row*E_ + tid*4) = o4;
}

// ---------------- 64x64 bf16 MFMA GEMM, BK=64 (proven best for N=1024 ops) -------
// EPI: 1 = f32 out + bias + f32 res; 3 = bf16 out + bias + f32 res (proj);
//      4 = f32 out + bias + bf16 res (FFN2).
template<int BM, int BN, int EPI>
__global__ __launch_bounds__(256)
void gemm_t(const bf16* __restrict__ A, const bf16* __restrict__ Bt, void* Cout,
            const float* __restrict__ bias, const void* res,
            int M, int N, int K) {
    constexpr int MT = BM / 32;
    constexpr int NB = BN / 32;
    constexpr int MHALF = BM / 2, NHALF = BN / 2;
    __shared__ bf16 As[BM*64];
    __shared__ bf16 Bs[BN*64];
    int tid = threadIdx.x;
    int lane = tid & 63, w = tid >> 6;
    int wr = w >> 1, wc = w & 1;
    int nbx = gridDim.x;
    int hid = blockIdx.y * nbx + blockIdx.x;
    int cpx = (nbx * gridDim.y) >> 3;
    int nid = (hid & 7) * cpx + (hid >> 3);     // XCD-chunked (m157, bijective)
    int m0 = (nid / nbx) * BM, n0 = (nid % nbx) * BN;
    int lr = lane & 15, lq = lane >> 4;
    f32x4 acc[MT][NB] = {};
    int srow = w*8 + (lane >> 3);
    int schunk = ((lane & 7) ^ (srow & 7)) * 8;
    const bf16* Ap = A  + (size_t)(m0 + srow)*K + schunk;
    const bf16* Bp = Bt + (size_t)(n0 + srow)*K + schunk;
    for (int k0 = 0; k0 < K; k0 += 64) {
#pragma unroll
        for (int i = 0; i < BM/32; ++i)
            async_cp16(Ap + (size_t)(i*32)*K + k0, (char*)As + i*4096 + w*1024);
#pragma unroll
        for (int i = 0; i < BN/32; ++i)
            async_cp16(Bp + (size_t)(i*32)*K + k0, (char*)Bs + i*4096 + w*1024);
        __syncthreads();
        const char* Asb = (const char*)As;
        const char* Bsb = (const char*)Bs;
        s16x8 af[2][MT], bfr[2][NB];
#pragma unroll
        for (int m = 0; m < MT; ++m) {
            int row = wr*MHALF + m*16 + lr;
            int base = row*128, sw = (row & 7) << 4;
#pragma unroll
            for (int kk = 0; kk < 2; ++kk)
                af[kk][m] = *reinterpret_cast<const s16x8*>(Asb + base + ((kk*64 + lq*16) ^ sw));
        }
#pragma unroll
        for (int n = 0; n < NB; ++n) {
            int row = wc*NHALF + n*16 + lr;
            int base = row*128, sw = (row & 7) << 4;
#pragma unroll
            for (int kk = 0; kk < 2; ++kk)
                bfr[kk][n] = *reinterpret_cast<const s16x8*>(Bsb + base + ((kk*64 + lq*16) ^ sw));
        }
        __builtin_amdgcn_s_setprio(1);
#pragma unroll
        for (int kk = 0; kk < 2; ++kk)
#pragma unroll
            for (int m = 0; m < MT; ++m)
#pragma unroll
                for (int n = 0; n < NB; ++n)
                    acc[m][n] = MFMA16(af[kk][m], bfr[kk][n], acc[m][n]);
        __builtin_amdgcn_s_setprio(0);
        __syncthreads();
    }
#pragma unroll
    for (int m = 0; m < MT; ++m) {
#pragma unroll
        for (int n = 0; n < NB; ++n) {
            int col = n0 + wc*NHALF + n*16 + lr;
#pragma unroll
            for (int r = 0; r < 4; ++r) {
                int row = m0 + wr*MHALF + m*16 + lq*4 + r;
                size_t idx = (size_t)row*N + col;
                float v = acc[m][n][r] + bias[col];
                if (EPI == 1) {
                    reinterpret_cast<float*>(Cout)[idx] =
                        v + reinterpret_cast<const float*>(res)[idx];
                } else if (EPI == 3) {
                    reinterpret_cast<bf16*>(Cout)[idx] =
                        __float2bfloat16(v + reinterpret_cast<const float*>(res)[idx]);
                } else {   // EPI == 4
                    reinterpret_cast<float*>(Cout)[idx] =
                        v + bf2f(reinterpret_cast<const unsigned short*>(res)[idx]);
                }
            }
        }
    }
}

// ---------------- 256x256 8-wave 4-phase-lookahead GEMM (QKV / FFN1) ------------
#define RD(p) (*reinterpret_cast<const s16x8*>(p))
#define MM(m,n) do { acc[m][n] = MFMA16(af[m][0], bfr[n][0], acc[m][n]); \
                     acc[m][n] = MFMA16(af[m][1], bfr[n][1], acc[m][n]); } while (0)
#define MFMAS_0 MM(0,0); MM(1,0);
#define MFMAS_1 MM(2,0); MM(3,0); MM(2,1); MM(3,1); MM(0,1); MM(1,1);
#define MFMAS_2 MM(4,0); MM(5,0); MM(4,1); MM(5,1); MM(4,2); MM(5,2); \
                MM(0,2); MM(1,2); MM(2,2); MM(3,2);
#define MFMAS_3 MM(6,0); MM(7,0); MM(6,1); MM(7,1); MM(6,2); MM(7,2); \
                MM(6,3); MM(7,3); MM(0,3); MM(1,3); MM(2,3); MM(3,3); \
                MM(4,3); MM(5,3);

template<int EPI>
__global__ __launch_bounds__(512)
void gemm8p(const bf16* __restrict__ A, const bf16* __restrict__ Bt, void* Cout,
            const float* __restrict__ bias, int M, int N, int K) {
    __shared__ char smem[131072];   // buf b at b*65536: A 32K | B 32K
    int tid = threadIdx.x;
    int lane = tid & 63, w = tid >> 6;
    int wm = w >> 2, wn = w & 3;
    int nbx = gridDim.x;
    int hid = blockIdx.y * nbx + blockIdx.x;
    int cpx = (nbx * gridDim.y) >> 3;
    int nid = (hid & 7) * cpx + (hid >> 3);     // XCD-chunked (m157, bijective)
    int m0 = (nid / nbx) * 256, n0 = (nid % nbx) * 256;
    int lr = lane & 15, lq = lane >> 4;
    f32x4 acc[8][4] = {};
    int srow = tid >> 3;
    int schunk = ((tid & 7) ^ (srow & 7)) * 8;
    const bf16* ApS = A  + (size_t)(m0 + srow)*K + schunk;
    const bf16* BpS = Bt + (size_t)(n0 + srow)*K + schunk;
    int sw4 = (lr & 7) << 4;
    int x0 = (lq*16) ^ sw4, x1 = (64 + lq*16) ^ sw4;
    int aoff[8], boff[4];
#pragma unroll
    for (int m = 0; m < 8; ++m)
        aoff[m] = ((m >> 1)*64 + wm*32 + (m & 1)*16 + lr) * 128;
#pragma unroll
    for (int n = 0; n < 4; ++n)
        boff[n] = (n*64 + wn*16 + lr) * 128;
    int nst = K >> 6;
    s16x8 af[8][2], bfr[4][2];
#pragma unroll
    for (int q = 0; q < 4; ++q) {
        async_cp16(ApS + (size_t)(q*64)*K, smem + q*8192 + w*1024);
        async_cp16(BpS + (size_t)(q*64)*K, smem + 32768 + q*8192 + w*1024);
    }
    ApS += 64; BpS += 64;
    asm volatile("s_waitcnt vmcnt(6)" ::: "memory");
    __builtin_amdgcn_sched_barrier(0);
    __builtin_amdgcn_s_barrier();
    __builtin_amdgcn_sched_barrier(0);

#define PHASE(Q) do {                                                              \
    af[2*Q][0]   = RD(bufA + aoff[2*Q]   + x0);                                    \
    af[2*Q][1]   = RD(bufA + aoff[2*Q]   + x1);                                    \
    af[2*Q+1][0] = RD(bufA + aoff[2*Q+1] + x0);                                    \
    af[2*Q+1][1] = RD(bufA + aoff[2*Q+1] + x1);                                    \
    bfr[Q][0]    = RD(bufB + boff[Q] + x0);                                        \
    bfr[Q][1]    = RD(bufB + boff[Q] + x1);                                        \
    if (more) {                                                                    \
        async_cp16(ApS + (size_t)(Q*64)*K, stA + Q*8192 + w*1024);                 \
        async_cp16(BpS + (size_t)(Q*64)*K, stA + 32768 + Q*8192 + w*1024);         \
        asm volatile("s_waitcnt vmcnt(6)" ::: "memory");                           \
    } else {                                                                       \
        if (Q == 0) asm volatile("s_waitcnt vmcnt(4)" ::: "memory");               \
        else if (Q == 1) asm volatile("s_waitcnt vmcnt(2)" ::: "memory");          \
        else if (Q == 2) asm volatile("s_waitcnt vmcnt(0)" ::: "memory");          \
    }                                                                              \
    __builtin_amdgcn_sched_barrier(0);                                             \
    __builtin_amdgcn_s_barrier();                                                  \
    __builtin_amdgcn_sched_barrier(0);                                             \
    asm volatile("s_waitcnt lgkmcnt(0)" ::: "memory");                             \
    __builtin_amdgcn_sched_barrier(0);                                             \
    __builtin_amdgcn_s_setprio(1);                                                 \
    MFMAS_##Q                                                                      \
    __builtin_amdgcn_s_setprio(0);                                                 \
    __builtin_amdgcn_sched_barrier(0);                                             \
    __builtin_amdgcn_s_barrier();                                                  \
    __builtin_amdgcn_sched_barrier(0);                                             \
} while (0)

    for (int t = 0; t < nst; ++t) {
        const char* bufA = smem + (size_t)(t & 1)*65536;
        const char* bufB = bufA + 32768;
        char* stA = smem + (size_t)((t & 1) ^ 1)*65536;
        bool more = (t + 1 < nst);
        PHASE(0);
        PHASE(1);
        PHASE(2);
        PHASE(3);
        ApS += 64; BpS += 64;
    }
#undef PHASE
#pragma unroll
    for (int m = 0; m < 8; ++m) {
#pragma unroll
        for (int n = 0; n < 4; ++n) {
            int col = n0 + n*64 + wn*16 + lr;
#pragma unroll
            for (int r = 0; r < 4; ++r) {
                int row = m0 + (m >> 1)*64 + wm*32 + (m & 1)*16 + lq*4 + r;
                float v = acc[m][n][r];
                if (EPI == 0) {
                    reinterpret_cast<bf16*>(Cout)[(size_t)row*N + col] = __float2bfloat16(v);
                } else {
                    v += bias[col];
                    v = v > 0.f ? v : 0.f;
                    reinterpret_cast<bf16*>(Cout)[(size_t)row*N + col] = __float2bfloat16(v);
                }
            }
        }
    }
}

// ---------------- V transpose: qkv v-section -> Vt [B,H,HD,T] ----------------
__global__ __launch_bounds__(256) void v_transpose(const bf16* __restrict__ qkv,
                                                   bf16* __restrict__ Vt) {
    __shared__ unsigned short tile[32][33];
    int tx = threadIdx.x, ty = threadIdx.y;
    int bh = blockIdx.z;
    int b = bh >> 4, h = bh & 15;
    int t0 = blockIdx.x * 32, d0 = blockIdx.y * 32;
    const unsigned short* src = reinterpret_cast<const unsigned short*>(qkv);
#pragma unroll
    for (int i = 0; i < 4; ++i)
        tile[ty + i*8][tx] = src[(size_t)(b*T_ + t0 + ty + i*8)*3072 + 2048 + h*64 + d0 + tx];
    __syncthreads();
    unsigned short* dst = reinterpret_cast<unsigned short*>(Vt);
#pragma unroll
    for (int i = 0; i < 4; ++i)
        dst[(size_t)(bh*64 + d0 + ty + i*8)*T_ + t0 + tx] = tile[tx][ty + i*8];
}

// ---------------- causal flash attention v8 (r11-best) --------------------------
__global__ __launch_bounds__(256)
void flash_attn(const bf16* __restrict__ qkv, const bf16* __restrict__ Vt,
                bf16* __restrict__ O) {
    __shared__ char smem[40960];   // K dbuf 16K | V dbuf 16K | P 4x2K
    int tid = threadIdx.x;
    int lane = tid & 63, w = tid >> 6;
    int lr = lane & 15, lq = lane >> 4;
    int bh = blockIdx.y, b = bh >> 4, h = bh & 15;
    int pm = (bh & 15) ^ ((bh & 16) ? 31 : 0);
    int qt = (int)(blockIdx.x ^ pm) & 31;         // complement-paired depths per CU
    int q0 = qt * 64;
    int qw = q0 + w * 16;
    const bf16* Qb = qkv + (size_t)(b*T_)*3072 + h*HD_;
    const bf16* Kb = Qb + 1024;
    const bf16* Vb = Vt + (size_t)bh * HD_ * T_;
    char* Pw = smem + 32768 + w*2048;

    int srow_ = w*8 + (lane >> 3);
    int sc_   = (((lane & 7) ^ (srow_ & 7))) * 8;
    const bf16* kS0 = Kb + (size_t)srow_*3072 + sc_;
    const bf16* kS1 = kS0 + (size_t)32*3072;
    const bf16* vS0 = Vb + (size_t)srow_*2048 + sc_;
    const bf16* vS1 = vS0 + (size_t)32*2048;
    char* kD = smem + w*1024;
    char* vD = smem + 16384 + w*1024;

    int sw4 = (lr & 7) << 4;
    int kvo[4], pwo[4];
#pragma unroll
    for (int n = 0; n < 4; ++n) {
        kvo[n] = n*2048 + lr*128 + ((lq << 4) ^ sw4);
        pwo[n] = (lr*128 + n*32 + lq*8) ^ sw4;
    }
    int pao0 = (lr*128 + lq*16) ^ sw4;
    int pao1 = (lr*128 + 64 + lq*16) ^ sw4;

    s16x8 qf[2];
#pragma unroll
    for (int kk = 0; kk < 2; ++kk)
        qf[kk] = *reinterpret_cast<const s16x8*>(Qb + (size_t)(qw + lr)*3072 + kk*32 + lq*8);
    f32x4 od[4] = {};
    const f32x4 Z4 = {0.f, 0.f, 0.f, 0.f};
    float lrun = 0.f;
    int ntiles = qt + 1;

    auto stageNext = [&](int bufi) {
        async_cp16(kS0, kD + bufi*8192);
        async_cp16(kS1, kD + bufi*8192 + 4096);
        async_cp16(vS0, vD + bufi*8192);
        async_cp16(vS1, vD + bufi*8192 + 4096);
        kS0 += 64*3072; kS1 += 64*3072; vS0 += 64; vS1 += 64;
    };

    auto step = [&](const char* Kt, const char* Vtl, bool diag, int kv0) {
        f32x4 sc[4];
        __builtin_amdgcn_s_setprio(1);
#pragma unroll
        for (int n = 0; n < 4; ++n) {
            s16x8 kf0 = *reinterpret_cast<const s16x8*>(Kt + kvo[n]);
            s16x8 kf1 = *reinterpret_cast<const s16x8*>(Kt + (kvo[n] ^ 64));
            f32x4 z = MFMA16(kf0, qf[0], Z4);   // S^T: col=q(lr), row=kv
            z = MFMA16(kf1, qf[1], z);
            sc[n] = z;
        }
        __builtin_amdgcn_s_setprio(0);
        if (diag) {
            int q = qw + lr;
#pragma unroll
            for (int n = 0; n < 4; ++n)
#pragma unroll
                for (int r = 0; r < 4; ++r)
                    if (kv0 + n*16 + lq*4 + r > q) sc[n][r] = -1e30f;
        }
        float psum = 0.f;
#pragma unroll
        for (int n = 0; n < 4; ++n) {
            float p0 = exp2_fast(sc[n][0]);
            float p1 = exp2_fast(sc[n][1]);
            float p2 = exp2_fast(sc[n][2]);
            float p3 = exp2_fast(sc[n][3]);
            psum += (p0 + p1) + (p2 + p3);
            uint2 pk;
            pk.x = cvt_pk_bf16(p0, p1);
            pk.y = cvt_pk_bf16(p2, p3);
            *reinterpret_cast<uint2*>(Pw + pwo[n]) = pk;
        }
        psum += __shfl_xor(psum, 16);
        psum += __shfl_xor(psum, 32);
        lrun += psum;
        asm volatile("" ::: "memory");
        s16x8 pa0 = *reinterpret_cast<const s16x8*>(Pw + pao0);
        s16x8 pa1 = *reinterpret_cast<const s16x8*>(Pw + pao1);
        __builtin_amdgcn_s_setprio(1);
#pragma unroll
        for (int nd = 0; nd < 4; ++nd) {
            s16x8 vf0 = *reinterpret_cast<const s16x8*>(Vtl + kvo[nd]);
            s16x8 vf1 = *reinterpret_cast<const s16x8*>(Vtl + (kvo[nd] ^ 64));
            od[nd] = MFMA16(pa0, vf0, od[nd]);
            od[nd] = MFMA16(pa1, vf1, od[nd]);
        }
        __builtin_amdgcn_s_setprio(0);
    };

    stageNext(0);
    for (int it = 0; it < ntiles - 1; ++it) {
        int curb = it & 1;
        stageNext(curb ^ 1);
        asm volatile("s_waitcnt vmcnt(4)" ::: "memory");
        __builtin_amdgcn_sched_barrier(0);
        __builtin_amdgcn_s_barrier();
        __builtin_amdgcn_sched_barrier(0);
        step(smem + curb*8192, smem + 16384 + curb*8192, false, 0);
        __builtin_amdgcn_sched_barrier(0);
        __builtin_amdgcn_s_barrier();
        __builtin_amdgcn_sched_barrier(0);
    }
    {   // peeled diagonal step
        int curb = (ntiles - 1) & 1;
        asm volatile("s_waitcnt vmcnt(0)" ::: "memory");
        __builtin_amdgcn_sched_barrier(0);
        __builtin_amdgcn_s_barrier();
        __builtin_amdgcn_sched_barrier(0);
        step(smem + curb*8192, smem + 16384 + curb*8192, true, (ntiles - 1) * 64);
    }
    float lR[4];
#pragma unroll
    for (int r = 0; r < 4; ++r) lR[r] = 1.0f / __shfl(lrun, lq*4 + r);
#pragma unroll
    for (int nd = 0; nd < 4; ++nd) {
#pragma unroll
        for (int r = 0; r < 4; ++r) {
            int row = qw + lq*4 + r;
            O[(size_t)(b*T_ + row)*E_ + h*HD_ + nd*16 + lr] = __float2bfloat16(od[nd][r] * lR[r]);
        }
    }
}

// ---------------- launch ----------------
extern "C" void kernel_launch(void* const* d_in, const int* in_sizes, int n_in,
                              void* d_out, int out_size, void* d_ws, size_t ws_size,
                              hipStream_t stream) {
    const float* x   = (const float*)d_in[0];
    const float* Wk  = (const float*)d_in[1];
    const float* Wq  = (const float*)d_in[2];
    const float* Wv  = (const float*)d_in[3];
    const float* Wp  = (const float*)d_in[4];
    const float* bp  = (const float*)d_in[5];
    const float* W1  = (const float*)d_in[6];
    const float* b1  = (const float*)d_in[7];
    const float* W2  = (const float*)d_in[8];
    const float* b2  = (const float*)d_in[9];
    const float* g1  = (const float*)d_in[10];
    const float* be1 = (const float*)d_in[11];
    const float* g2  = (const float*)d_in[12];
    const float* be2 = (const float*)d_in[13];
    float* out = (float*)d_out;

    char* ws = (char*)d_ws;
    bf16* Wqkv_t = (bf16*)(ws + 0);          //  6 MB [3072][1024] (+Wp_t after)
    bf16* Wp_t   = (bf16*)(ws + 6291456);    //  2 MB [1024][1024]
    bf16* W1_t   = (bf16*)(ws + 8388608);    //  8 MB [4096][1024]
    bf16* W2_t   = (bf16*)(ws + 16777216);   //  8 MB [1024][4096]
    bf16* h      = (bf16*)(ws + 25165824);   //  8 MB [4096][1024] (reused as h2)
    bf16* qkv    = (bf16*)(ws + 33554432);   // 24 MB [4096][3072]
    bf16* Vt     = (bf16*)(ws + 58720256);   //  8 MB [B,H,HD,T]
    bf16* attnO  = (bf16*)(ws + 67108864);   //  8 MB [4096][1024]
    bf16* ff1    = (bf16*)(ws + 33554432);   // 32 MB, reuses qkv+Vt (dead after flash)
    bool big = ws_size >= 83886080;
    bf16* x2b = (bf16*)(ws + 75497472);      //  8 MB bf16 residual (big path)

    dim3 tb(32, 8);
    transpose_all<<<12288, tb, 0, stream>>>(Wq, Wk, Wv, Wp, W1, W2, Wqkv_t, W1_t, W2_t);

    ln_kernel<<<NT, 256, 0, stream>>>(x, g1, be1, h);
    gemm8p<0><<<dim3(12, 16), 512, 0, stream>>>(h, Wqkv_t, qkv, nullptr, NT, 3072, 1024);
    v_transpose<<<dim3(64, 2, 32), tb, 0, stream>>>(qkv, Vt);
    flash_attn<<<dim3(32, 32), 256, 0, stream>>>(qkv, Vt, attnO);
    if (big) {
        gemm_t<64,64,3><<<dim3(16, 64), 256, 0, stream>>>(attnO, Wp_t, x2b, bp, x, NT, 1024, 1024);
        ln_kernel_b<<<NT, 256, 0, stream>>>(x2b, g2, be2, h);
        gemm8p<2><<<dim3(16, 16), 512, 0, stream>>>(h, W1_t, ff1, b1, NT, 4096, 1024);
        gemm_t<64,64,4><<<dim3(16, 64), 256, 0, stream>>>(ff1, W2_t, out, b2, x2b, NT, 1024, 4096);
    } else {
        gemm_t<64,64,1><<<dim3(16, 64), 256, 0, stream>>>(attnO, Wp_t, out, bp, x, NT, 1024, 1024);
        ln_kernel<<<NT, 256, 0, stream>>>(out, g2, be2, h);
        gemm8p<2><<<dim3(16, 16), 512, 0, stream>>>(h, W1_t, ff1, b1, NT, 4096, 1024);
        gemm_t<64,64,1><<<dim3(16, 64), 256, 0, stream>>>(ff1, W2_t, out, b2, out, NT, 1024, 4096);
    }
}